// Round 1
// baseline (149.865 us; speedup 1.0000x reference)
//
#include <hip/hip_runtime.h>
#include <math.h>

#define BLOCK 256

__global__ __launch_bounds__(BLOCK) void traj_cost_kernel(
    const float* __restrict__ pos,    // (N, 3)
    const float* __restrict__ rot,    // (N, 3, 3)
    const float* __restrict__ gpos,   // (H, 3)
    const float* __restrict__ grot,   // (H, 3, 3)
    float* __restrict__ out,          // cost[N] | rot_err_norm[N] | goal_dist[N]
    long long N, int H)
{
    __shared__ float s_rot[BLOCK * 9];   // 9216 B
    __shared__ float s_pos[BLOCK * 3];   // 3072 B
    __shared__ float s_grot[BLOCK * 9];  // 9216 B  goal rows this block needs
    __shared__ float s_gpos[BLOCK * 3];  // 3072 B  -> 24.6 KiB total, 6 blk/CU

    const int tid = threadIdx.x;
    const long long base = (long long)blockIdx.x * BLOCK;

    if (base + BLOCK <= N) {
        // Fast path: stage 256 poses. rot chunk = 2304 floats = 576 float4,
        // pos chunk = 768 floats = 192 float4. Fully coalesced.
        const float4* r4 = (const float4*)(rot + base * 9);
        float4* s4 = (float4*)s_rot;
        s4[tid]        = r4[tid];
        s4[tid + 256]  = r4[tid + 256];
        if (tid < 64) s4[tid + 512] = r4[tid + 512];
        const float4* p4 = (const float4*)(pos + base * 3);
        float4* sp4 = (float4*)s_pos;
        if (tid < 192) sp4[tid] = p4[tid];
    } else {
        const int nel = (int)(N - base);
        for (int k = tid; k < nel * 9; k += BLOCK) s_rot[k] = rot[base * 9 + k];
        for (int k = tid; k < nel * 3; k += BLOCK) s_pos[k] = pos[base * 3 + k];
    }

    // Stage the goal rows this block touches, with COALESCED copies.
    // Rows needed: (h0 + k) % H for k in [0, BLOCK). For H >= BLOCK that is
    // at most two contiguous row ranges [h0, h0+len1) and [0, len2) -> two
    // linear segment copies; slot k then holds exactly row (h0+k)%H, so the
    // compute phase uses slot = tid with no per-thread modulo at all.
    // Previously each lane read its own grot row directly from global:
    // 9 loads/thread x 36 cache lines/wave-load of L1 replay — that, not
    // HBM, was pacing the kernel.
    const int h0 = (int)(base % (long long)H);   // uniform, once per block
    if (H >= BLOCK) {
        const int len1 = (H - h0 < BLOCK) ? (H - h0) : BLOCK;
        const int len2 = BLOCK - len1;
        for (int k = tid; k < len1 * 9; k += BLOCK) s_grot[k] = grot[h0 * 9 + k];
        for (int k = tid; k < len2 * 9; k += BLOCK) s_grot[len1 * 9 + k] = grot[k];
        for (int k = tid; k < len1 * 3; k += BLOCK) s_gpos[k] = gpos[h0 * 3 + k];
        for (int k = tid; k < len2 * 3; k += BLOCK) s_gpos[len1 * 3 + k] = gpos[k];
    } else {
        // Small H: stage the whole goal arrays at identity slots.
        for (int k = tid; k < H * 9; k += BLOCK) s_grot[k] = grot[k];
        for (int k = tid; k < H * 3; k += BLOCK) s_gpos[k] = gpos[k];
    }
    __syncthreads();

    const long long idx = base + tid;
    if (idx >= N) return;

    int slot;
    if (H >= BLOCK) {
        slot = tid;                       // see staging comment
    } else {
        int h = h0 + tid;
        slot = h % H;                     // 32-bit mod, small-H path only
    }

    // LDS reads: word-stride 9 / 3 across lanes -> every bank hit exactly
    // twice per wave64 = free 2-way aliasing on gfx950 (both pose and goal).
    float R[9], P[3], G[9], GP[3];
    #pragma unroll
    for (int c = 0; c < 9; ++c) R[c] = s_rot[tid * 9 + c];
    #pragma unroll
    for (int c = 0; c < 3; ++c) P[c] = s_pos[tid * 3 + c];
    #pragma unroll
    for (int c = 0; c < 9; ++c) G[c] = s_grot[slot * 9 + c];
    #pragma unroll
    for (int c = 0; c < 3; ++c) GP[c] = s_gpos[slot * 3 + c];

    // t[i] = ee_t_g[i] = -sum_j G[j,i]*GP[j] + sum_j R[j,i]*P[j]
    float t[3];
    #pragma unroll
    for (int i = 0; i < 3; ++i) {
        float a = 0.f;
        #pragma unroll
        for (int j = 0; j < 3; ++j)
            a += R[j * 3 + i] * P[j] - G[j * 3 + i] * GP[j];
        t[i] = a;
    }
    // pos_weight == (1,1,1)
    float pos_err = t[0] * t[0] + t[1] * t[1] + t[2] * t[2];
    float goal_dist = pos_err > 0.f ? sqrtf(pos_err) : 0.f;

    // ee_R_g[i,j] = sum_k G[k,i] * R[k,j]; d = I - ee_R_g
    float rn[3];
    #pragma unroll
    for (int i = 0; i < 3; ++i) {
        float q = 0.f;
        #pragma unroll
        for (int j = 0; j < 3; ++j) {
            float m = G[0 * 3 + i] * R[0 * 3 + j]
                    + G[1 * 3 + i] * R[1 * 3 + j]
                    + G[2 * 3 + i] * R[2 * 3 + j];
            float d = (i == j ? 1.f : 0.f) - m;
            q += d * d;
        }
        rn[i] = q > 0.f ? sqrtf(q) : 0.f;   // row_norm, rot_weight == 1
    }
    float s  = rn[0] + rn[1] + rn[2];
    float q2 = rn[0] * rn[0] + rn[1] * rn[1] + rn[2] * rn[2];
    float rot_err_norm = q2 > 0.f ? sqrtf(q2) : 0.f;

    // rot_err = s^2 (s >= 0), hinged on goal_dist <= 100; convergence
    // thresholds are 0 (no-op on non-negative values).
    // cost = safe_sqrt(rot_err) + safe_sqrt(pos_err) = (hinge ? s : 0) + goal_dist
    // -- sqrt(s*s) == s since s >= 0, so the sqrt is free.
    float cost = (goal_dist <= 100.0f ? s : 0.f) + goal_dist;

    out[idx]         = cost;
    out[N + idx]     = rot_err_norm;
    out[2 * N + idx] = goal_dist;
}

extern "C" void kernel_launch(void* const* d_in, const int* in_sizes, int n_in,
                              void* d_out, int out_size, void* d_ws, size_t ws_size,
                              hipStream_t stream) {
    const float* pos  = (const float*)d_in[0];
    const float* rot  = (const float*)d_in[1];
    const float* gpos = (const float*)d_in[2];
    const float* grot = (const float*)d_in[3];
    float* out = (float*)d_out;

    const long long N = (long long)in_sizes[0] / 3;   // B*H poses
    const int H = in_sizes[2] / 3;

    const int blocks = (int)((N + BLOCK - 1) / BLOCK);
    traj_cost_kernel<<<blocks, BLOCK, 0, stream>>>(pos, rot, gpos, grot, out, N, H);
}

// Round 2
// 142.736 us; speedup vs baseline: 1.0499x; 1.0499x over previous
//
#include <hip/hip_runtime.h>
#include <math.h>

#define BLOCK 256
#define SUBT 256            // poses per subtile (== BLOCK)
#define BUF_WORDS 3072      // per buffer: 2304 rot floats + 768 pos floats
#define GOAL_ROW 13         // 9 rot + 3 pos + 1 pad; gcd(13,32)=1 -> conflict-free LDS reads

typedef unsigned int u32;

// Async global->LDS DMA, 16B per lane. LDS dest is wave-uniform base + lane*16
// (hardware-defined); global src carries the per-lane offset. This removes the
// VGPR round-trip and the staging VALU loops entirely.
__device__ __forceinline__ void async_lds16(float* lds, const float* g) {
  __builtin_amdgcn_global_load_lds(
      (const __attribute__((address_space(1))) u32*)g,
      (__attribute__((address_space(3))) u32*)lds, 16, 0, 0);
}

__device__ __forceinline__ void stage_subtile_dma(float* buf,
                                                  const float* __restrict__ rot,
                                                  const float* __restrict__ pos,
                                                  u32 base, int wave, int lane) {
  // 12 chunks of 1KB (64 lanes x 16B): 9 rot + 3 pos. Wave w takes chunks w, w+4, w+8.
  const float* rsrc = rot + (size_t)base * 9;
  const float* psrc = pos + (size_t)base * 3;
  #pragma unroll
  for (int i = 0; i < 3; ++i) {
    const int c = wave + 4 * i;                 // wave-uniform
    if (c < 9) async_lds16(buf + c * 256, rsrc + c * 256 + lane * 4);
    else       async_lds16(buf + 2304 + (c - 9) * 256, psrc + (c - 9) * 256 + lane * 4);
  }
}

__device__ __forceinline__ void stage_subtile_tail(float* buf,
                                                   const float* __restrict__ rot,
                                                   const float* __restrict__ pos,
                                                   u32 base, long long N, int tid) {
  const u32 n = (u32)(N - (long long)base);     // < 256
  for (u32 k = tid; k < n * 9; k += BLOCK) buf[k] = rot[(size_t)base * 9 + k];
  for (u32 k = tid; k < n * 3; k += BLOCK) buf[2304 + k] = pos[(size_t)base * 3 + k];
}

__global__ __launch_bounds__(BLOCK) void traj_cost_kernel(
    const float* __restrict__ pos,    // (N, 3)
    const float* __restrict__ rot,    // (N, 3, 3)
    const float* __restrict__ gpos,   // (H, 3)
    const float* __restrict__ grot,   // (H, 3, 3)
    float* __restrict__ out,          // cost[N] | rot_err_norm[N] | goal_dist[N]
    long long N, int H, int hstaged)
{
  extern __shared__ float smem[];               // [buf0 3072][buf1 3072][goals 13*H]
  float* sg = smem + 2 * BUF_WORDS;

  const int tid  = threadIdx.x;
  const int wave = tid >> 6, lane = tid & 63;

  const u32 nsub   = (u32)((N + SUBT - 1) / SUBT);
  u32 s            = blockIdx.x;                // grid-stride over subtiles
  const u32 stride = gridDim.x;

  // ---- goal staging, once per block (one-time 12KB read; L2-hit) ----
  if (hstaged) {
    for (u32 r = tid; r < (u32)H; r += BLOCK) {
      #pragma unroll
      for (int j = 0; j < 9; ++j) sg[r * GOAL_ROW + j] = grot[r * 9u + j];
      #pragma unroll
      for (int j = 0; j < 3; ++j) sg[r * GOAL_ROW + 9 + j] = gpos[r * 3u + j];
    }
  }

  // ---- prologue: stage first subtile ----
  {
    const u32 base = s * SUBT;
    if ((long long)base + SUBT <= N) stage_subtile_dma(smem, rot, pos, base, wave, lane);
    else                             stage_subtile_tail(smem, rot, pos, base, N, tid);
  }
  __syncthreads();   // compiler emits vmcnt(0) drain before s_barrier -> DMA complete

  // h = (s*SUBT + tid) % H once; then incremental wrap (hstep < H).
  u32 h = (s * SUBT + (u32)tid) % (u32)H;
  const u32 hstep = (u32)(((unsigned long long)stride * SUBT) % (u32)H);

  float* __restrict__ o1 = out + N;
  float* __restrict__ o2 = out + 2 * N;
  int cur = 0;

  for (;;) {
    const u32 snext = s + stride;

    // Issue next subtile's DMA BEFORE compute: its latency hides under the
    // compute phase; the end-of-loop barrier drains it.
    if (snext < nsub) {
      float* nbuf = smem + (cur ^ 1) * BUF_WORDS;
      const u32 base = snext * SUBT;
      if ((long long)base + SUBT <= N) stage_subtile_dma(nbuf, rot, pos, base, wave, lane);
      else                             stage_subtile_tail(nbuf, rot, pos, base, N, tid);
    }

    // ---- compute current subtile ----
    const long long idx = (long long)s * SUBT + tid;
    if (idx < N) {
      const float* buf = smem + cur * BUF_WORDS;
      float R[9], P[3], G[9], GP[3];
      // pose reads: lane word-stride 9 / 3, gcd(9,32)=gcd(3,32)=1 -> free 2-way
      #pragma unroll
      for (int c = 0; c < 9; ++c) R[c] = buf[tid * 9 + c];
      #pragma unroll
      for (int c = 0; c < 3; ++c) P[c] = buf[2304 + tid * 3 + c];
      if (hstaged) {
        // goal reads: lane h-stride 1, row stride 13 -> all 32 banks, free 2-way
        #pragma unroll
        for (int c = 0; c < 9; ++c) G[c] = sg[h * GOAL_ROW + c];
        #pragma unroll
        for (int c = 0; c < 3; ++c) GP[c] = sg[h * GOAL_ROW + 9 + c];
      } else {
        #pragma unroll
        for (int c = 0; c < 9; ++c) G[c] = grot[(size_t)h * 9 + c];
        #pragma unroll
        for (int c = 0; c < 3; ++c) GP[c] = gpos[(size_t)h * 3 + c];
      }

      // t[i] = -sum_j G[j,i]*GP[j] + sum_j R[j,i]*P[j]
      float t[3];
      #pragma unroll
      for (int i = 0; i < 3; ++i) {
        float a = 0.f;
        #pragma unroll
        for (int j = 0; j < 3; ++j)
          a += R[j * 3 + i] * P[j] - G[j * 3 + i] * GP[j];
        t[i] = a;
      }
      const float pos_err = t[0] * t[0] + t[1] * t[1] + t[2] * t[2];
      const float goal_dist = pos_err > 0.f ? __builtin_amdgcn_sqrtf(pos_err) : 0.f;

      // ee_R_g[i,j] = sum_k G[k,i]*R[k,j]; d = I - ee_R_g
      float rn[3];
      #pragma unroll
      for (int i = 0; i < 3; ++i) {
        float q = 0.f;
        #pragma unroll
        for (int j = 0; j < 3; ++j) {
          float m = G[0 * 3 + i] * R[0 * 3 + j]
                  + G[1 * 3 + i] * R[1 * 3 + j]
                  + G[2 * 3 + i] * R[2 * 3 + j];
          float d = (i == j ? 1.f : 0.f) - m;
          q += d * d;
        }
        rn[i] = q > 0.f ? __builtin_amdgcn_sqrtf(q) : 0.f;
      }
      const float ssum = rn[0] + rn[1] + rn[2];
      const float q2 = rn[0] * rn[0] + rn[1] * rn[1] + rn[2] * rn[2];
      const float rot_err_norm = q2 > 0.f ? __builtin_amdgcn_sqrtf(q2) : 0.f;

      // cost = (hinge ? s : 0) + goal_dist   (sqrt(s^2)==s, s>=0; thresholds 0 = no-op)
      const float cost = (goal_dist <= 100.0f ? ssum : 0.f) + goal_dist;

      out[idx] = cost;
      o1[idx]  = rot_err_norm;
      o2[idx]  = goal_dist;
    }

    if (snext >= nsub) break;
    __syncthreads();          // drains next-stage DMA; buf[cur] now free to overwrite
    cur ^= 1;
    s = snext;
    h += hstep; if (h >= (u32)H) h -= (u32)H;
  }
}

extern "C" void kernel_launch(void* const* d_in, const int* in_sizes, int n_in,
                              void* d_out, int out_size, void* d_ws, size_t ws_size,
                              hipStream_t stream) {
  const float* pos  = (const float*)d_in[0];
  const float* rot  = (const float*)d_in[1];
  const float* gpos = (const float*)d_in[2];
  const float* grot = (const float*)d_in[3];
  float* out = (float*)d_out;

  const long long N = (long long)in_sizes[0] / 3;   // B*H poses
  const int H = in_sizes[2] / 3;

  const u32 nsub = (u32)((N + SUBT - 1) / SUBT);
  const int blocks = (int)(nsub < 1024u ? nsub : 1024u);   // persistent: 4 blocks/CU
  const int hstaged = (H <= 1024) ? 1 : 0;
  const size_t smem = (size_t)(2 * BUF_WORDS + (hstaged ? GOAL_ROW * H : 0)) * sizeof(float);

  traj_cost_kernel<<<blocks, BLOCK, smem, stream>>>(pos, rot, gpos, grot, out,
                                                    N, H, hstaged);
}